// Round 1
// baseline (432.597 us; speedup 1.0000x reference)
//
#include <hip/hip_runtime.h>
#include <math.h>

#define DD 128
#define KK 8
#define LN_EPS 1e-5f
#define NORM_EPS 1e-12f

// Row-per-thread fused kernel:
//   h = x @ W^T + b  (streamed, never stored)
//   LayerNorm -> l2norm -> cosine logits vs normalized codebook -> softmax/argmax
// Per-row state is 13 streaming accumulators (linear/quadratic functionals of h),
// so h[128] never needs registers/LDS. W is read with wave-uniform addresses from
// LDS (pure broadcast, no bank conflicts).
__global__ __launch_bounds__(256, 2)
void l1q_kernel(const float* __restrict__ x, const float* __restrict__ W,
                const float* __restrict__ b, const float* __restrict__ gamma,
                const float* __restrict__ beta, const float* __restrict__ cb,
                float* __restrict__ out_idx, float* __restrict__ out_soft,
                float* __restrict__ out_emb, float* __restrict__ out_log,
                int B)
{
    __shared__ float Wl[DD * DD];        // 64 KB, row-major, uniform-broadcast reads
    __shared__ float coef[DD * 12];      // per-j: wg[8], g^2, g*b, bias_j, pad
    __shared__ float invn[KK];
    __shared__ float pk[KK], q0k[KK];
    __shared__ float cg2s, cgbs, cb2s;
    __shared__ int   bestl[256];

    const int t = threadIdx.x;
    const int row = blockIdx.x * 256 + t;

    // ---- stage W -> LDS (coalesced float4) ----
    {
        const float4* W4 = (const float4*)W;
        float4* Wl4 = (float4*)Wl;
        #pragma unroll
        for (int i = 0; i < (DD * DD / 4) / 256; ++i)
            Wl4[t + i * 256] = W4[t + i * 256];
    }

    // ---- load this thread's x row into registers (issue early to hide latency) ----
    float xr[DD];
    if (row < B) {
        const float4* xp = (const float4*)(x + (size_t)row * DD);
        #pragma unroll
        for (int i = 0; i < DD / 4; ++i) {
            float4 v = xp[i];
            xr[4 * i + 0] = v.x; xr[4 * i + 1] = v.y;
            xr[4 * i + 2] = v.z; xr[4 * i + 3] = v.w;
        }
    } else {
        #pragma unroll
        for (int i = 0; i < DD; ++i) xr[i] = 0.f;
    }

    // ---- codebook row norms ----
    if (t < KK) {
        float s = 0.f;
        #pragma unroll 8
        for (int j = 0; j < DD; ++j) { float v = cb[t * DD + j]; s = fmaf(v, v, s); }
        invn[t] = 1.0f / fmaxf(sqrtf(s), NORM_EPS);
    }
    __syncthreads();

    // ---- per-j coefficient table ----
    if (t < DD) {
        float g = gamma[t], be = beta[t];
        #pragma unroll
        for (int k = 0; k < KK; ++k) coef[t * 12 + k] = cb[k * DD + t] * invn[k] * g;
        coef[t * 12 + 8]  = g * g;
        coef[t * 12 + 9]  = g * be;
        coef[t * 12 + 10] = b[t];
        coef[t * 12 + 11] = 0.f;
    }
    __syncthreads();

    // ---- per-block scalar reductions ----
    if (t < KK) {
        float p = 0.f, q = 0.f;
        for (int j = 0; j < DD; ++j) {
            p += coef[j * 12 + t];
            q = fmaf(cb[t * DD + j] * invn[t], beta[j], q);
        }
        pk[t] = p; q0k[t] = q;
    }
    if (t == 8)  { float s = 0.f; for (int j = 0; j < DD; ++j) { float g = gamma[j]; s = fmaf(g, g, s); } cg2s = s; }
    if (t == 9)  { float s = 0.f; for (int j = 0; j < DD; ++j) s = fmaf(gamma[j], beta[j], s); cgbs = s; }
    if (t == 10) { float s = 0.f; for (int j = 0; j < DD; ++j) { float v = beta[j]; s = fmaf(v, v, s); } cb2s = s; }
    __syncthreads();

    // ---- main streamed matvec over j ----
    float s1 = 0.f, s2 = 0.f, t1 = 0.f, t2 = 0.f, r1 = 0.f;
    float u[KK];
    #pragma unroll
    for (int k = 0; k < KK; ++k) u[k] = 0.f;

    for (int j = 0; j < DD; ++j) {
        const float4* wrow = (const float4*)(Wl + j * DD);   // uniform address
        float a0 = 0.f, a1 = 0.f, a2 = 0.f, a3 = 0.f;
        #pragma unroll
        for (int i = 0; i < DD / 4; ++i) {
            float4 w = wrow[i];
            a0 = fmaf(xr[4 * i + 0], w.x, a0);
            a1 = fmaf(xr[4 * i + 1], w.y, a1);
            a2 = fmaf(xr[4 * i + 2], w.z, a2);
            a3 = fmaf(xr[4 * i + 3], w.w, a3);
        }
        const float4* cf = (const float4*)(coef + j * 12);   // uniform address
        float4 c0 = cf[0], c1 = cf[1], c2 = cf[2];
        float h = ((a0 + a1) + (a2 + a3)) + c2.z;            // + b_j
        float h2 = h * h;
        s1 += h;
        s2 = fmaf(h, h, s2);
        t2 = fmaf(c2.x, h2, t2);
        t1 = fmaf(c2.x, h, t1);
        r1 = fmaf(c2.y, h, r1);
        u[0] = fmaf(c0.x, h, u[0]); u[1] = fmaf(c0.y, h, u[1]);
        u[2] = fmaf(c0.z, h, u[2]); u[3] = fmaf(c0.w, h, u[3]);
        u[4] = fmaf(c1.x, h, u[4]); u[5] = fmaf(c1.y, h, u[5]);
        u[6] = fmaf(c1.z, h, u[6]); u[7] = fmaf(c1.w, h, u[7]);
    }

    // ---- epilogue: logits, softmax, argmax ----
    const float invD = 1.0f / (float)DD;
    float mu = s1 * invD;
    float var = fmaf(-mu, mu, s2 * invD);
    float istd = 1.0f / sqrtf(var + LN_EPS);
    float nrm2 = istd * istd * (t2 - 2.f * mu * t1 + mu * mu * cg2s)
               + 2.f * istd * (r1 - mu * cgbs) + cb2s;
    float rinv = 1.0f / fmaxf(sqrtf(fmaxf(nrm2, 0.f)), NORM_EPS);

    float lg[KK];
    #pragma unroll
    for (int k = 0; k < KK; ++k)
        lg[k] = (istd * (u[k] - mu * pk[k]) + q0k[k]) * rinv;  // TEMPERATURE = 1

    float mx = lg[0]; int bi = 0;
    #pragma unroll
    for (int k = 1; k < KK; ++k) if (lg[k] > mx) { mx = lg[k]; bi = k; }

    float ex[KK], se = 0.f;
    #pragma unroll
    for (int k = 0; k < KK; ++k) { ex[k] = expf(lg[k] - mx); se += ex[k]; }
    float rse = 1.0f / se;

    if (row < B) {
        out_idx[row] = (float)bi;
        float4* os = (float4*)(out_soft + (size_t)row * KK);
        os[0] = make_float4(ex[0] * rse, ex[1] * rse, ex[2] * rse, ex[3] * rse);
        os[1] = make_float4(ex[4] * rse, ex[5] * rse, ex[6] * rse, ex[7] * rse);
        float4* ol = (float4*)(out_log + (size_t)row * KK);
        ol[0] = make_float4(lg[0], lg[1], lg[2], lg[3]);
        ol[1] = make_float4(lg[4], lg[5], lg[6], lg[7]);
    }
    bestl[t] = bi;
    __syncthreads();

    // ---- cooperative coalesced embedding write: emb[row] = codebook[best[row]] ----
    {
        const size_t base4 = (size_t)blockIdx.x * 256 * (DD / 4);
        float4* eo = (float4*)out_emb;
        const float4* cb4 = (const float4*)cb;
        #pragma unroll
        for (int i = 0; i < 32; ++i) {
            int e4 = t + i * 256;          // float4 index within block tile
            int r  = e4 >> 5;              // 32 float4 per row
            int d4 = e4 & 31;
            int rr = blockIdx.x * 256 + r;
            if (rr < B) eo[base4 + e4] = cb4[bestl[r] * 32 + d4];
        }
    }
}

extern "C" void kernel_launch(void* const* d_in, const int* in_sizes, int n_in,
                              void* d_out, int out_size, void* d_ws, size_t ws_size,
                              hipStream_t stream) {
    const float* x     = (const float*)d_in[0];
    const float* W     = (const float*)d_in[1];
    const float* b     = (const float*)d_in[2];
    const float* gamma = (const float*)d_in[3];
    const float* beta  = (const float*)d_in[4];
    const float* cb    = (const float*)d_in[5];
    const int B = in_sizes[0] / DD;

    float* out    = (float*)d_out;
    float* o_idx  = out;                              // (B,)
    float* o_soft = out + (size_t)B;                  // (B,K)
    float* o_emb  = out + (size_t)B * (1 + KK);       // (B,D)
    float* o_log  = out + (size_t)B * (1 + KK + DD);  // (B,K)

    const int grid = (B + 255) / 256;
    hipLaunchKernelGGL(l1q_kernel, dim3(grid), dim3(256), 0, stream,
                       x, W, b, gamma, beta, cb, o_idx, o_soft, o_emb, o_log, B);
}